// Round 1
// baseline (634.018 us; speedup 1.0000x reference)
//
#include <hip/hip_runtime.h>

// Problem: x (8,3,40,128,128) f32, W (16,3,3,3,3) f32, b (16) f32.
// y = conv3d VALID -> (8,16,38,126,126); softmax over C=16; maxpool 4x4x4
// truncating to (8,16,9,31,31). Only d<36,h<124,w<124 positions survive.
//
// Block = (b, do, ho, wtile of 16 pooled cells). 256 threads = 4(h) x 64(w).
// Each thread: 4 depth positions, 16 channels, conv from LDS x-tile,
// weights via wave-uniform s_load (SGPR-sourced FMAs), softmax + pool in regs.

__global__ __launch_bounds__(256, 4)
void conv_softmax_pool(const float* __restrict__ x,
                       const float* __restrict__ W,
                       const float* __restrict__ bias,
                       float* __restrict__ out) {
    const int bid = blockIdx.x;
    const int wt  = bid & 1;            // w-tile: 0 -> wo 0..15, 1 -> wo 16..30
    const int ho  = (bid >> 1) % 31;
    const int dpo = (bid / 62) % 9;
    const int b   = bid / 558;          // 558 = 2*31*9

    const int w0 = wt * 64;             // input w base
    const int h0 = ho * 4;
    const int d0 = dpo * 4;
    const int activeW = wt ? 60 : 64;   // valid conv w-positions in this tile (124 total)

    __shared__ float xs[3][6][6][66];   // [ci][d][h][w] 28.5 KB
    __shared__ float red[4][16][17];    // [ty][wc][ch] padded, 4.25 KB

    const int tid = threadIdx.x;

    // ---- stage x tile: 3*6*6*66 = 7128 floats ----
    const size_t xbase = (size_t)b * (3ull * 40 * 128 * 128);
    for (int idx = tid; idx < 3 * 6 * 6 * 66; idx += 256) {
        int w = idx % 66;
        int t = idx / 66;
        int h = t % 6;  t /= 6;
        int d = t % 6;
        int ci = t / 6;
        int gw = w0 + w;
        float v = 0.0f;
        if (gw < 128)
            v = x[xbase + ((size_t)ci * 40 + (d0 + d)) * 16384
                        + (size_t)(h0 + h) * 128 + gw];
        xs[ci][d][h][w] = v;
    }
    __syncthreads();

    const int tx = tid & 63;            // w position within tile
    const int ty = tid >> 6;            // h position within pooled row (wave id)

    float pmax[16];
    #pragma unroll
    for (int c = 0; c < 16; ++c) pmax[c] = -1e30f;

    #pragma unroll 1
    for (int dd = 0; dd < 4; ++dd) {
        float y[16];
        #pragma unroll
        for (int c = 0; c < 16; ++c) y[c] = bias[c];

        #pragma unroll
        for (int ci = 0; ci < 3; ++ci) {
            #pragma unroll
            for (int kd = 0; kd < 3; ++kd) {
                float xv[9];
                #pragma unroll
                for (int kh = 0; kh < 3; ++kh)
                    #pragma unroll
                    for (int kw = 0; kw < 3; ++kw)
                        xv[kh * 3 + kw] = xs[ci][dd + kd][ty + kh][tx + kw];
                #pragma unroll
                for (int oc = 0; oc < 16; ++oc) {
                    const float* wp = W + ((oc * 3 + ci) * 3 + kd) * 9; // uniform -> s_load
                    float acc = y[oc];
                    #pragma unroll
                    for (int t = 0; t < 9; ++t)
                        acc = fmaf(xv[t], wp[t], acc);
                    y[oc] = acc;
                }
            }
        }

        // softmax over 16 channels, then accumulate pooled max over depth
        float m = y[0];
        #pragma unroll
        for (int c = 1; c < 16; ++c) m = fmaxf(m, y[c]);
        float s = 0.0f;
        #pragma unroll
        for (int c = 0; c < 16; ++c) { y[c] = __expf(y[c] - m); s += y[c]; }
        float inv = 1.0f / s;
        #pragma unroll
        for (int c = 0; c < 16; ++c) pmax[c] = fmaxf(pmax[c], y[c] * inv);
    }

    // pool over w within each aligned group of 4 lanes
    #pragma unroll
    for (int c = 0; c < 16; ++c) {
        float v = pmax[c];
        v = fmaxf(v, __shfl_xor(v, 1));
        v = fmaxf(v, __shfl_xor(v, 2));
        pmax[c] = v;
    }
    if (tx < activeW && (tx & 3) == 0) {
        int wc = tx >> 2;
        #pragma unroll
        for (int c = 0; c < 16; ++c) red[ty][wc][c] = pmax[c];
    }
    __syncthreads();

    // final reduce over the 4 h-rows and write output (coalesced in wo)
    {
        int ch = tid >> 4;
        int wc = tid & 15;
        int wo = wt * 16 + wc;
        if (wo < 31) {
            float v =         red[0][wc][ch];
            v = fmaxf(v, red[1][wc][ch]);
            v = fmaxf(v, red[2][wc][ch]);
            v = fmaxf(v, red[3][wc][ch]);
            out[(((size_t)b * 16 + ch) * 9 + dpo) * 961 + (size_t)ho * 31 + wo] = v;
        }
    }
}

extern "C" void kernel_launch(void* const* d_in, const int* in_sizes, int n_in,
                              void* d_out, int out_size, void* d_ws, size_t ws_size,
                              hipStream_t stream) {
    const float* x  = (const float*)d_in[0];
    const float* W  = (const float*)d_in[1];
    const float* bb = (const float*)d_in[2];
    float* out = (float*)d_out;

    const int blocks = 8 * 9 * 31 * 2;  // 4464
    hipLaunchKernelGGL(conv_softmax_pool, dim3(blocks), dim3(256), 0, stream,
                       x, W, bb, out);
}

// Round 2
// 466.883 us; speedup vs baseline: 1.3580x; 1.3580x over previous
//
#include <hip/hip_runtime.h>

// x (8,3,40,128,128) f32, W (16,3,3,3,3) f32, b (16) f32.
// conv3d VALID -> softmax(C=16) -> 4x4x4 truncating maxpool -> (8,16,9,31,31).
//
// R2: (a) __launch_bounds__(256,2) to stop accumulator spilling (R1: 95 MB
// scratch writes at VGPR=52); (b) pack the two depth positions of each pooled
// cell into float2 and use v_pk_fma_f32 (weights duplicated {w,w} in d_ws,
// read via wave-uniform s_load pairs -> one SGPR source per VOP3P, legal).

typedef float v2f __attribute__((ext_vector_type(2)));

__global__ void dup_weights(const float* __restrict__ W, float* __restrict__ wd) {
    int i = blockIdx.x * 256 + threadIdx.x;     // 81*16 = 1296 entries
    if (i < 81 * 16) {
        int oc  = i & 15;
        int tap = i >> 4;                        // (ci*3+kd)*9 + t
        int ci = tap / 27, r = tap % 27, kd = r / 9, t = r % 9;
        float w = W[((oc * 3 + ci) * 3 + kd) * 9 + t];
        wd[2 * i]     = w;
        wd[2 * i + 1] = w;
    }
}

template<int PAIRED>
__global__ __launch_bounds__(256, 2)
void conv_softmax_pool(const float* __restrict__ x,
                       const float* __restrict__ W,
                       const float* __restrict__ bias,
                       const v2f* __restrict__ wd,
                       float* __restrict__ out) {
    const int bid = blockIdx.x;
    const int wt  = bid & 1;            // w-tile: 0 -> wo 0..15, 1 -> wo 16..30
    const int ho  = (bid >> 1) % 31;
    const int dpo = (bid / 62) % 9;
    const int b   = bid / 558;          // 558 = 2*31*9

    const int w0 = wt * 64;
    const int h0 = ho * 4;
    const int d0 = dpo * 4;
    const int activeW = wt ? 60 : 64;

    __shared__ float xs[3][6][6][66];   // 28.5 KB
    __shared__ float red[4][16][17];    // 4.25 KB

    const int tid = threadIdx.x;

    // ---- stage x tile ----
    const size_t xbase = (size_t)b * (3ull * 40 * 128 * 128);
    for (int idx = tid; idx < 3 * 6 * 6 * 66; idx += 256) {
        int w = idx % 66;
        int t = idx / 66;
        int h = t % 6;  t /= 6;
        int d = t % 6;
        int ci = t / 6;
        int gw = w0 + w;
        float v = 0.0f;
        if (gw < 128)
            v = x[xbase + ((size_t)ci * 40 + (d0 + d)) * 16384
                        + (size_t)(h0 + h) * 128 + gw];
        xs[ci][d][h][w] = v;
    }
    __syncthreads();

    const int tx = tid & 63;
    const int ty = tid >> 6;

    v2f pm2[16];
    #pragma unroll
    for (int c = 0; c < 16; ++c) pm2[c] = (v2f){-1e30f, -1e30f};

    #pragma unroll 1
    for (int dp = 0; dp < 2; ++dp) {    // two depth-pairs: dd = {0,1}, {2,3}
        const int dd = dp * 2;

        v2f y2[16];
        #pragma unroll
        for (int c = 0; c < 16; ++c) { float bb = bias[c]; y2[c] = (v2f){bb, bb}; }

        #pragma unroll
        for (int ci = 0; ci < 3; ++ci) {
            #pragma unroll
            for (int kd = 0; kd < 3; ++kd) {
                v2f xv2[9];
                #pragma unroll
                for (int kh = 0; kh < 3; ++kh)
                    #pragma unroll
                    for (int kw = 0; kw < 3; ++kw)
                        xv2[kh * 3 + kw] =
                            (v2f){ xs[ci][dd + kd][ty + kh][tx + kw],
                                   xs[ci][dd + 1 + kd][ty + kh][tx + kw] };

                const int tb = (ci * 3 + kd) * 9;
                #pragma unroll
                for (int t = 0; t < 9; ++t) {
                    #pragma unroll
                    for (int oc = 0; oc < 16; ++oc) {
                        v2f w2;
                        if constexpr (PAIRED) {
                            w2 = wd[(tb + t) * 16 + oc];      // uniform -> s_load x2
                        } else {
                            float w = W[((oc * 3 + ci) * 3 + kd) * 9 + t];
                            w2 = (v2f){w, w};
                        }
                        y2[oc] = __builtin_elementwise_fma(xv2[t], w2, y2[oc]);
                    }
                }
            }
        }

        // packed softmax over 16 channels + pooled-max accumulate
        v2f m2 = y2[0];
        #pragma unroll
        for (int c = 1; c < 16; ++c) m2 = __builtin_elementwise_max(m2, y2[c]);
        v2f s2 = (v2f){0.0f, 0.0f};
        #pragma unroll
        for (int c = 0; c < 16; ++c) {
            v2f e = y2[c] - m2;
            y2[c] = (v2f){__expf(e.x), __expf(e.y)};
            s2 += y2[c];
        }
        v2f inv = (v2f){1.0f / s2.x, 1.0f / s2.y};
        #pragma unroll
        for (int c = 0; c < 16; ++c)
            pm2[c] = __builtin_elementwise_max(pm2[c], y2[c] * inv);
    }

    // pool over w within each aligned group of 4 lanes
    float pmax[16];
    #pragma unroll
    for (int c = 0; c < 16; ++c) {
        float v = fmaxf(pm2[c].x, pm2[c].y);   // depth pool done
        v = fmaxf(v, __shfl_xor(v, 1));
        v = fmaxf(v, __shfl_xor(v, 2));
        pmax[c] = v;
    }
    if (tx < activeW && (tx & 3) == 0) {
        int wc = tx >> 2;
        #pragma unroll
        for (int c = 0; c < 16; ++c) red[ty][wc][c] = pmax[c];
    }
    __syncthreads();

    // reduce over 4 h-rows, write coalesced
    {
        int ch = tid >> 4;
        int wc = tid & 15;
        int wo = wt * 16 + wc;
        if (wo < 31) {
            float v =         red[0][wc][ch];
            v = fmaxf(v, red[1][wc][ch]);
            v = fmaxf(v, red[2][wc][ch]);
            v = fmaxf(v, red[3][wc][ch]);
            out[(((size_t)b * 16 + ch) * 9 + dpo) * 961 + (size_t)ho * 31 + wo] = v;
        }
    }
}

extern "C" void kernel_launch(void* const* d_in, const int* in_sizes, int n_in,
                              void* d_out, int out_size, void* d_ws, size_t ws_size,
                              hipStream_t stream) {
    const float* x  = (const float*)d_in[0];
    const float* W  = (const float*)d_in[1];
    const float* bb = (const float*)d_in[2];
    float* out = (float*)d_out;

    const int blocks = 8 * 9 * 31 * 2;  // 4464
    const size_t WBYTES = 81 * 16 * 2 * sizeof(float);  // 10368 B

    if (ws_size >= WBYTES) {
        hipLaunchKernelGGL(dup_weights, dim3(6), dim3(256), 0, stream,
                           W, (float*)d_ws);
        hipLaunchKernelGGL((conv_softmax_pool<1>), dim3(blocks), dim3(256), 0, stream,
                           x, W, bb, (const v2f*)d_ws, out);
    } else {
        hipLaunchKernelGGL((conv_softmax_pool<0>), dim3(blocks), dim3(256), 0, stream,
                           x, W, bb, (const v2f*)d_ws, out);
    }
}

// Round 3
// 175.475 us; speedup vs baseline: 3.6131x; 2.6607x over previous
//
#include <hip/hip_runtime.h>

// x (8,3,40,128,128) f32, W (16,3,3,3,3) f32, b (16) f32.
// conv3d VALID -> softmax(C=16) -> 4x4x4 truncating maxpool -> (8,16,9,31,31).
//
// R3: kill spills + packing overhead.
//  - LDS x-tile stored depth-innermost xs[ci][h][w][6] so each packed
//    depth-pair operand is adjacent floats (ds_read2_b32, no v_movs).
//  - Depth fully unrolled: ya[16] (depths d0,d0+1) and yb[16] (d0+2,d0+3)
//    accumulate in straight-line code; every weight v2f s_loaded once,
//    used by 2 v_pk_fma_f32; every x pair reused 16x.
//  - Only the ci loop is rolled (I-cache), accumulators legitimately live.
//  - Weights duplicated {w,w} in d_ws, layout [ci][kd][tap][oc].

typedef float v2f __attribute__((ext_vector_type(2)));

__global__ void dup_weights(const float* __restrict__ W, float* __restrict__ wd) {
    int i = blockIdx.x * 256 + threadIdx.x;     // 81*16 = 1296 entries
    if (i < 81 * 16) {
        int oc  = i & 15;
        int tap = i >> 4;                        // ((ci*3+kd)*9 + t)
        int ci = tap / 27, r = tap % 27, kd = r / 9, t = r % 9;
        float w = W[((oc * 3 + ci) * 3 + kd) * 9 + t];
        wd[2 * i]     = w;
        wd[2 * i + 1] = w;
    }
}

template<int PAIRED>
__global__ __launch_bounds__(256, 2)
void conv_softmax_pool(const float* __restrict__ x,
                       const float* __restrict__ W,
                       const float* __restrict__ bias,
                       const v2f* __restrict__ wd,
                       float* __restrict__ out) {
    const int bid = blockIdx.x;
    const int wt  = bid & 1;            // w-tile: 0 -> wo 0..15, 1 -> wo 16..30
    const int ho  = (bid >> 1) % 31;
    const int dpo = (bid / 62) % 9;
    const int b   = bid / 558;          // 558 = 2*31*9

    const int w0 = wt * 64;
    const int h0 = ho * 4;
    const int d0 = dpo * 4;
    const int activeW = wt ? 60 : 64;

    __shared__ float xs[3][6][66][6];   // [ci][h][w][d]  27.8 KB
    __shared__ float red[4][16][17];    // 4.25 KB

    const int tid = threadIdx.x;

    // ---- stage x tile (read coalesced in w, write d-innermost) ----
    const size_t xbase = (size_t)b * (3ull * 40 * 128 * 128);
    for (int idx = tid; idx < 3 * 6 * 6 * 66; idx += 256) {
        int w = idx % 66;
        int t = idx / 66;
        int h = t % 6;  t /= 6;
        int d = t % 6;
        int ci = t / 6;
        int gw = w0 + w;
        float v = 0.0f;
        if (gw < 128)
            v = x[xbase + ((size_t)ci * 40 + (d0 + d)) * 16384
                        + (size_t)(h0 + h) * 128 + gw];
        xs[ci][h][w][d] = v;
    }
    __syncthreads();

    const int tx = tid & 63;
    const int ty = tid >> 6;

    v2f ya[16], yb[16];                 // depths (d0,d0+1) and (d0+2,d0+3)
    #pragma unroll
    for (int c = 0; c < 16; ++c) { float bb = bias[c]; ya[c] = (v2f){bb, bb}; yb[c] = ya[c]; }

    #pragma unroll 1
    for (int ci = 0; ci < 3; ++ci) {
        #pragma unroll
        for (int kd = 0; kd < 3; ++kd) {
            #pragma unroll
            for (int kh = 0; kh < 3; ++kh) {
                #pragma unroll
                for (int kw = 0; kw < 3; ++kw) {
                    const float* xp = &xs[ci][ty + kh][tx + kw][0];
                    v2f xa, xb;
                    xa.x = xp[kd];     xa.y = xp[kd + 1];
                    xb.x = xp[kd + 2]; xb.y = xp[kd + 3];

                    const int t = kh * 3 + kw;
                    v2f wloc[16];
                    if constexpr (PAIRED) {
                        const v2f* wp = wd + ((ci * 3 + kd) * 9 + t) * 16;
                        #pragma unroll
                        for (int oc = 0; oc < 16; ++oc) wloc[oc] = wp[oc];
                    } else {
                        #pragma unroll
                        for (int oc = 0; oc < 16; ++oc) {
                            float w = W[((oc * 3 + ci) * 3 + kd) * 9 + t];
                            wloc[oc] = (v2f){w, w};
                        }
                    }
                    #pragma unroll
                    for (int oc = 0; oc < 16; ++oc) {
                        ya[oc] = __builtin_elementwise_fma(xa, wloc[oc], ya[oc]);
                        yb[oc] = __builtin_elementwise_fma(xb, wloc[oc], yb[oc]);
                    }
                }
            }
        }
    }

    // packed softmax over 16 channels for both depth pairs
    v2f ma = ya[0], mb = yb[0];
    #pragma unroll
    for (int c = 1; c < 16; ++c) {
        ma = __builtin_elementwise_max(ma, ya[c]);
        mb = __builtin_elementwise_max(mb, yb[c]);
    }
    v2f sa = (v2f){0.f, 0.f}, sb = sa;
    #pragma unroll
    for (int c = 0; c < 16; ++c) {
        v2f ea = ya[c] - ma, eb = yb[c] - mb;
        ya[c] = (v2f){__expf(ea.x), __expf(ea.y)};
        yb[c] = (v2f){__expf(eb.x), __expf(eb.y)};
        sa += ya[c]; sb += yb[c];
    }
    v2f inva = (v2f){1.0f / sa.x, 1.0f / sa.y};
    v2f invb = (v2f){1.0f / sb.x, 1.0f / sb.y};

    // depth pool + w pool (groups of 4 lanes)
    float pmax[16];
    #pragma unroll
    for (int c = 0; c < 16; ++c) {
        v2f pa = ya[c] * inva, pb = yb[c] * invb;
        v2f m = __builtin_elementwise_max(pa, pb);
        float v = fmaxf(m.x, m.y);
        v = fmaxf(v, __shfl_xor(v, 1));
        v = fmaxf(v, __shfl_xor(v, 2));
        pmax[c] = v;
    }
    if (tx < activeW && (tx & 3) == 0) {
        int wc = tx >> 2;
        #pragma unroll
        for (int c = 0; c < 16; ++c) red[ty][wc][c] = pmax[c];
    }
    __syncthreads();

    // reduce over 4 h-rows, write coalesced
    {
        int ch = tid >> 4;
        int wc = tid & 15;
        int wo = wt * 16 + wc;
        if (wo < 31) {
            float v =         red[0][wc][ch];
            v = fmaxf(v, red[1][wc][ch]);
            v = fmaxf(v, red[2][wc][ch]);
            v = fmaxf(v, red[3][wc][ch]);
            out[(((size_t)b * 16 + ch) * 9 + dpo) * 961 + (size_t)ho * 31 + wo] = v;
        }
    }
}

extern "C" void kernel_launch(void* const* d_in, const int* in_sizes, int n_in,
                              void* d_out, int out_size, void* d_ws, size_t ws_size,
                              hipStream_t stream) {
    const float* x  = (const float*)d_in[0];
    const float* W  = (const float*)d_in[1];
    const float* bb = (const float*)d_in[2];
    float* out = (float*)d_out;

    const int blocks = 8 * 9 * 31 * 2;  // 4464
    const size_t WBYTES = 81 * 16 * 2 * sizeof(float);  // 10368 B

    if (ws_size >= WBYTES) {
        hipLaunchKernelGGL(dup_weights, dim3(6), dim3(256), 0, stream,
                           W, (float*)d_ws);
        hipLaunchKernelGGL((conv_softmax_pool<1>), dim3(blocks), dim3(256), 0, stream,
                           x, W, bb, (const v2f*)d_ws, out);
    } else {
        hipLaunchKernelGGL((conv_softmax_pool<0>), dim3(blocks), dim3(256), 0, stream,
                           x, W, bb, (const v2f*)d_ws, out);
    }
}